// Round 4
// baseline (97.713 us; speedup 1.0000x reference)
//
#include <hip/hip_runtime.h>
#include <math.h>

#define NB_TOTAL 65536
#define NOBS 256
#define OUTS 773            // 2 + 514 + 257
#define PSTRIDE 16          // floats per row in ws

typedef float f32x4 __attribute__((ext_vector_type(4)));
typedef float f32x2 __attribute__((ext_vector_type(2)));

// Output row layout (f32):
//  [0..1]    x31
//  [2+2j]    G_s[j][0], [3+2j] G_s[j][1]   j in 0..255   -> 2..513
//  [514,515] G_o
//  [516+j]   h_s[j]                                      -> 516..771
//  [772]     h_o
//
// ws row layout (16 f32):
//  [0]px [1]py [2]tvs [3]tvc | [4]tc [5]ts [6]hc [7]x31_0
//  [8]x31_1 [9]Go0 [10]Go1 [11]0 | [12]ps [13]pp [14]ho [15]0

// skewed LDS index: breaks power-of-2 bank strides
#define SKW(i) ((i) + ((i) >> 4))

// ---------------------------------------------------------------------------
// K1: wave-pair per 64 rows. role0 -> x21/x31 branch + dynamics + params;
//     role1 -> x22/x32 branch + dynamics + (ps,pp,ho).
// ---------------------------------------------------------------------------
__global__ __launch_bounds__(256) void k1_mlp(
    const float* __restrict__ x,
    const float* __restrict__ input_mean, const float* __restrict__ input_std,
    const float* __restrict__ W1,  const float* __restrict__ b1,
    const float* __restrict__ W21, const float* __restrict__ b21,
    const float* __restrict__ W22, const float* __restrict__ b22,
    const float* __restrict__ W31, const float* __restrict__ b31,
    const float* __restrict__ W32, const float* __restrict__ b32,
    float* __restrict__ ws)
{
    const int gt   = blockIdx.x * 256 + threadIdx.x;     // 0..131071
    const int lane = gt & 63;
    int role = (gt >> 6) & 1;
    role = __builtin_amdgcn_readfirstlane(role);          // wave-uniform
    const int row  = ((gt >> 7) << 6) | lane;             // each row hit by both roles

    float xr[8];
    {
        const float4 xa = *(const float4*)(x + (size_t)row * 8);
        const float4 xb = *(const float4*)(x + (size_t)row * 8 + 4);
        xr[0]=xa.x; xr[1]=xa.y; xr[2]=xa.z; xr[3]=xa.w;
        xr[4]=xb.x; xr[5]=xb.y; xr[6]=xb.z; xr[7]=xb.w;
    }

    const float* Wh = role ? W22 : W21;
    const float* bh = role ? b22 : b21;
    const float* Wo = role ? W32 : W31;
    const float* bo = role ? b32 : b31;

    float acc[32];
    #pragma unroll
    for (int k = 0; k < 32; ++k) acc[k] = bh[k];

    #pragma unroll 1
    for (int i0 = 0; i0 < 128; i0 += 8) {
        float hh[8];
        #pragma unroll
        for (int u = 0; u < 8; ++u) {
            float a = b1[i0 + u];
            #pragma unroll
            for (int k = 0; k < 8; ++k)
                a = fmaf(xr[k], W1[k * 128 + i0 + u], a);
            hh[u] = fmaxf(a, 0.0f);
        }
        #pragma unroll
        for (int u = 0; u < 8; ++u) {
            #pragma unroll
            for (int k = 0; k < 32; ++k)
                acc[k] = fmaf(hh[u], Wh[(i0 + u) * 32 + k], acc[k]);
        }
    }
    float o0 = bo[0], o1 = bo[1];
    #pragma unroll
    for (int k = 0; k < 32; ++k) {
        float a = fmaxf(acc[k], 0.0f);
        o0 = fmaf(a, Wo[k * 2 + 0], o0);
        o1 = fmaf(a, Wo[k * 2 + 1], o1);
    }

    // ---- dynamics (both roles, cheap) ----
    float x0v[8];
    #pragma unroll
    for (int k = 0; k < 8; ++k)
        x0v[k] = fmaf(xr[k], input_std[k], input_mean[k]);
    const float px = x0v[0], py = x0v[1], th = x0v[2], v = x0v[3];
    const float opx = x0v[4], opy = x0v[5], oth = x0v[6], ov = x0v[7];

    float st, ct, sto, cto;
    sincosf(th,  &st,  &ct);
    sincosf(oth, &sto, &cto);

    const float tvs = 2.0f * v * st;
    const float tvc = 2.0f * v * ct;
    const float tc  = 2.0f * ct;
    const float ts  = 2.0f * st;
    const float hc  = 2.0f * v * v;

    const float dxo = px - opx, dyo = py - opy;

    float* wp = ws + (size_t)row * PSTRIDE;

    if (role == 0) {
        const float Go0 = dxo * tvs - dyo * tvc;
        const float Go1 = -(dxo * tc + dyo * ts);
        *(float4*)(wp + 0) = make_float4(px, py, tvs, tvc);
        *(float4*)(wp + 4) = make_float4(tc, ts, hc, o0);
        *(float4*)(wp + 8) = make_float4(o1, Go0, Go1, 0.0f);
    } else {
        const float p0 = 4.0f / (1.0f + __expf(-o0));
        const float p1 = 4.0f / (1.0f + __expf(-o1));
        const float ps = p0 + p1;
        const float pp = p0 * p1;
        const float ob  = dxo * dxo + dyo * dyo - 1.21f;     // Ro^2 = 1.1^2
        const float rvx = v * ct - ov * cto;
        const float rvy = v * st - ov * sto;
        const float obd = 2.0f * (dxo * rvx + dyo * rvy);
        const float cth_sum = ct * cto - st * sto;            // cos(th + oth)
        const float oLf2b = 2.0f * (v * v + ov * ov - 2.0f * v * ov * cth_sum);
        const float ho = oLf2b + ps * obd + pp * ob;
        *(float4*)(wp + 12) = make_float4(ps, pp, ho, 0.0f);
    }
}

// ---------------------------------------------------------------------------
// K2: one wave per row; row's 3092B span written as aligned 16B chunks via
// NONTEMPORAL stores (bypass L2 allocate — the memset path runs at 6.6 TB/s).
// ---------------------------------------------------------------------------
__global__ __launch_bounds__(256, 8) void k2_fill(
    const float* __restrict__ obstacles,
    const float* __restrict__ ws,
    float* __restrict__ out)
{
    __shared__ float oxs[SKW(255) + 1], oys[SKW(255) + 1], r2s[SKW(255) + 1];
    __shared__ float prm[16][16];

    const int tid = threadIdx.x;
    {
        const float* o = obstacles + (size_t)tid * 3;
        const float a = o[0], b = o[1], r = o[2] + 0.6f;   // R = 0.5 + rad + 0.1
        const int s = SKW(tid);
        oxs[s] = a; oys[s] = b; r2s[s] = r * r;
    }
    {
        const int rloc = tid >> 4, k = tid & 15;
        prm[rloc][k] = ws[((size_t)blockIdx.x * 16 + rloc) * PSTRIDE + k];
    }
    __syncthreads();

    const int l  = tid & 63;
    const int wv = __builtin_amdgcn_readfirstlane(tid >> 6);

    #pragma unroll 1
    for (int rr = 0; rr < 4; ++rr) {
        const int rloc = wv * 4 + rr;
        const int row  = blockIdx.x * 16 + rloc;

        const float4 pa = *(const float4*)&prm[rloc][0];   // px,py,tvs,tvc
        const float4 pb = *(const float4*)&prm[rloc][4];   // tc,ts,hc,x31_0
        const float4 pc = *(const float4*)&prm[rloc][8];   // x31_1,Go0,Go1,-
        const float4 pd = *(const float4*)&prm[rloc][12];  // ps,pp,ho,-
        const float px = pa.x, py = pa.y, tvs = pa.z, tvc = pa.w;
        const float tc = pb.x, ts = pb.y, hc  = pb.z, x31_0 = pb.w;
        const float x31_1 = pc.x, Go0 = pc.y, Go1 = pc.z;
        const float ps = pd.x, pp = pd.y, ho = pd.z;

        const unsigned base = (unsigned)row * 773u;               // dword index
        const unsigned a0   = base & ~3u;
        const unsigned nch  = (((base + 773u + 3u) & ~3u) - a0) >> 2;  // 194/195

        #pragma unroll
        for (int q = 0; q < 4; ++q) {
            const unsigned c = (unsigned)(q * 64 + l);
            if (c < nch) {
                const int f0 = (int)(a0 + 4u * c) - (int)base;    // -3..775
                float vv[4];

                const bool pureG = (f0 >= 2)   && (f0 <= 510);    // f0+3 <= 513
                const bool pureH = (f0 >= 516) && (f0 <= 768);    // f0+3 <= 771

                if (pureG) {
                    #pragma unroll
                    for (int t = 0; t < 4; ++t) {
                        const int f  = f0 + t;
                        const int sk = SKW((f - 2) >> 1);
                        const float dx = px - oxs[sk];
                        const float dy = py - oys[sk];
                        vv[t] = (f & 1) ? -fmaf(dx, tc, dy * ts)
                                        :  fmaf(dx, tvs, -(dy * tvc));
                    }
                } else if (pureH) {
                    #pragma unroll
                    for (int t = 0; t < 4; ++t) {
                        const int sk = SKW(f0 + t - 516);
                        const float dx = px - oxs[sk];
                        const float dy = py - oys[sk];
                        const float bdot = fmaf(dx, tvc, dy * tvs);
                        const float bar  = fmaf(dx, dx, dy * dy) - r2s[sk];
                        vv[t] = fmaf(ps, bdot, fmaf(pp, bar, hc));
                    }
                } else {
                    #pragma unroll
                    for (int t = 0; t < 4; ++t) {
                        const int f = f0 + t;
                        const bool isH = (f >= 516);
                        unsigned idx = isH ? (unsigned)(f - 516)
                                           : (((unsigned)(f - 2)) >> 1);
                        if (idx > 255u) idx = 255u;
                        const int sk = SKW((int)idx);
                        const float dx = px - oxs[sk];
                        const float dy = py - oys[sk];
                        float val;
                        if (isH) {
                            const float bdot = fmaf(dx, tvc, dy * tvs);
                            const float bar  = fmaf(dx, dx, dy * dy) - r2s[sk];
                            val = fmaf(ps, bdot, fmaf(pp, bar, hc));
                        } else {
                            val = (f & 1) ? -fmaf(dx, tc, dy * ts)
                                          :  fmaf(dx, tvs, -(dy * tvc));
                        }
                        // overrides: f in {0,1} -> x31; {514,515} -> Go; 772 -> ho
                        const bool lo = ((unsigned)f < 2u);
                        const bool ov = lo | ((f >> 1) == 257);
                        const float ovA = lo ? x31_0 : Go0;
                        const float ovB = lo ? x31_1 : Go1;
                        float ovv = (f & 1) ? ovB : ovA;
                        val = ov ? ovv : val;
                        val = (f == 772) ? ho : val;
                        vv[t] = val;
                    }
                }

                float* p = out + (a0 + 4u * c);
                if (f0 >= 0 && f0 <= 769) {
                    f32x4 v4 = { vv[0], vv[1], vv[2], vv[3] };
                    __builtin_nontemporal_store(v4, (f32x4*)p);    // aligned 16B
                } else if (f0 < 0) {
                    // head partial: valid t >= -f0
                    f32x2 hi2 = { vv[2], vv[3] };
                    if (f0 == -1) {
                        __builtin_nontemporal_store(vv[1], p + 1);
                        __builtin_nontemporal_store(hi2, (f32x2*)(p + 2));
                    } else if (f0 == -2) {
                        __builtin_nontemporal_store(hi2, (f32x2*)(p + 2));
                    } else {
                        __builtin_nontemporal_store(vv[3], p + 3);
                    }
                } else {
                    // tail partial: valid t <= 772 - f0
                    const int e = 772 - f0;                        // 0..2
                    f32x2 lo2 = { vv[0], vv[1] };
                    if (e == 2) {
                        __builtin_nontemporal_store(lo2, (f32x2*)p);
                        __builtin_nontemporal_store(vv[2], p + 2);
                    } else if (e == 1) {
                        __builtin_nontemporal_store(lo2, (f32x2*)p);
                    } else {
                        __builtin_nontemporal_store(vv[0], p);
                    }
                }
            }
        }
    }
}

// ---------------------------------------------------------------------------
// Fallback: fused single kernel (used only if ws too small)
// ---------------------------------------------------------------------------
__device__ __forceinline__ void mlp_dynamics(
    int row,
    const float* __restrict__ x,
    const float* __restrict__ input_mean, const float* __restrict__ input_std,
    const float* __restrict__ W1,  const float* __restrict__ b1,
    const float* __restrict__ W21, const float* __restrict__ b21,
    const float* __restrict__ W22, const float* __restrict__ b22,
    const float* __restrict__ W31, const float* __restrict__ b31,
    const float* __restrict__ W32, const float* __restrict__ b32,
    float* p /*16 floats out*/)
{
    float xr[8];
    {
        const float4 xa = *(const float4*)(x + (size_t)row * 8);
        const float4 xb = *(const float4*)(x + (size_t)row * 8 + 4);
        xr[0]=xa.x; xr[1]=xa.y; xr[2]=xa.z; xr[3]=xa.w;
        xr[4]=xb.x; xr[5]=xb.y; xr[6]=xb.z; xr[7]=xb.w;
    }
    float acc[32];
    #pragma unroll
    for (int k = 0; k < 32; ++k) acc[k] = b21[k];
    #pragma unroll 1
    for (int i0 = 0; i0 < 128; i0 += 8) {
        float hh[8];
        #pragma unroll
        for (int u = 0; u < 8; ++u) {
            float a = b1[i0 + u];
            #pragma unroll
            for (int k = 0; k < 8; ++k)
                a = fmaf(xr[k], W1[k * 128 + i0 + u], a);
            hh[u] = fmaxf(a, 0.0f);
        }
        #pragma unroll
        for (int u = 0; u < 8; ++u)
            #pragma unroll
            for (int k = 0; k < 32; ++k)
                acc[k] = fmaf(hh[u], W21[(i0 + u) * 32 + k], acc[k]);
    }
    float x31_0 = b31[0], x31_1 = b31[1];
    #pragma unroll
    for (int k = 0; k < 32; ++k) {
        float a21 = fmaxf(acc[k], 0.0f);
        x31_0 = fmaf(a21, W31[k * 2 + 0], x31_0);
        x31_1 = fmaf(a21, W31[k * 2 + 1], x31_1);
    }
    #pragma unroll
    for (int k = 0; k < 32; ++k) acc[k] = b22[k];
    #pragma unroll 1
    for (int i0 = 0; i0 < 128; i0 += 8) {
        float hh[8];
        #pragma unroll
        for (int u = 0; u < 8; ++u) {
            float a = b1[i0 + u];
            #pragma unroll
            for (int k = 0; k < 8; ++k)
                a = fmaf(xr[k], W1[k * 128 + i0 + u], a);
            hh[u] = fmaxf(a, 0.0f);
        }
        #pragma unroll
        for (int u = 0; u < 8; ++u)
            #pragma unroll
            for (int k = 0; k < 32; ++k)
                acc[k] = fmaf(hh[u], W22[(i0 + u) * 32 + k], acc[k]);
    }
    float z0 = b32[0], z1 = b32[1];
    #pragma unroll
    for (int k = 0; k < 32; ++k) {
        float a22 = fmaxf(acc[k], 0.0f);
        z0 = fmaf(a22, W32[k * 2 + 0], z0);
        z1 = fmaf(a22, W32[k * 2 + 1], z1);
    }
    const float p0 = 4.0f / (1.0f + __expf(-z0));
    const float p1 = 4.0f / (1.0f + __expf(-z1));
    float x0v[8];
    #pragma unroll
    for (int k = 0; k < 8; ++k)
        x0v[k] = fmaf(xr[k], input_std[k], input_mean[k]);
    const float px = x0v[0], py = x0v[1], th = x0v[2], v = x0v[3];
    const float opx = x0v[4], opy = x0v[5], oth = x0v[6], ov = x0v[7];
    float st, ct, sto, cto;
    sincosf(th,  &st,  &ct);
    sincosf(oth, &sto, &cto);
    const float ps  = p0 + p1;
    const float pp  = p0 * p1;
    const float tvs = 2.0f * v * st;
    const float tvc = 2.0f * v * ct;
    const float tc  = 2.0f * ct;
    const float ts  = 2.0f * st;
    const float hc  = 2.0f * v * v;
    const float dxo = px - opx, dyo = py - opy;
    const float ob  = dxo * dxo + dyo * dyo - 1.21f;
    const float rvx = v * ct - ov * cto;
    const float rvy = v * st - ov * sto;
    const float obd = 2.0f * (dxo * rvx + dyo * rvy);
    const float cth_sum = ct * cto - st * sto;
    const float oLf2b = 2.0f * (v * v + ov * ov - 2.0f * v * ov * cth_sum);
    const float Go0 = dxo * tvs - dyo * tvc;
    const float Go1 = -(dxo * tc + dyo * ts);
    const float hov = oLf2b + ps * obd + pp * ob;
    p[0]=px;  p[1]=py;  p[2]=tvs; p[3]=tvc;
    p[4]=tc;  p[5]=ts;  p[6]=ps;  p[7]=pp;
    p[8]=hc;  p[9]=x31_0; p[10]=x31_1; p[11]=Go0;
    p[12]=Go1; p[13]=hov; p[14]=0.0f; p[15]=0.0f;
}

__global__ __launch_bounds__(256, 4) void fused_kernel(
    const float* __restrict__ x,
    const float* __restrict__ obstacles,
    const float* __restrict__ input_mean, const float* __restrict__ input_std,
    const float* __restrict__ W1,  const float* __restrict__ b1,
    const float* __restrict__ W21, const float* __restrict__ b21,
    const float* __restrict__ W22, const float* __restrict__ b22,
    const float* __restrict__ W31, const float* __restrict__ b31,
    const float* __restrict__ W32, const float* __restrict__ b32,
    float* __restrict__ out)
{
    __shared__ float params[64][16];
    const int tid = threadIdx.x;
    const int blockBase = blockIdx.x * 64;

    if (tid < 64) {
        const int row = blockBase + tid;
        float p[16];
        mlp_dynamics(row, x, input_mean, input_std,
                     W1, b1, W21, b21, W22, b22, W31, b31, W32, b32, p);
        float* rb = out + (size_t)row * OUTS;
        rb[0] = p[9]; rb[1] = p[10]; rb[514] = p[11]; rb[515] = p[12]; rb[772] = p[13];
        #pragma unroll
        for (int k = 0; k < 16; ++k) params[tid][k] = p[k];
    }
    __syncthreads();

    const int lane = tid & 63;
    const int wave = tid >> 6;
    float ox[4], oy[4], r2[4];
    #pragma unroll
    for (int c = 0; c < 4; ++c) {
        const float* o = obstacles + (size_t)(c * 64 + lane) * 3;
        const float a = o[0], b = o[1], r = o[2] + 0.6f;
        ox[c] = a; oy[c] = b; r2[c] = r * r;
    }
    #pragma unroll 1
    for (int rr = 0; rr < 16; ++rr) {
        const int rl = wave * 16 + rr;
        const float4 pA = *(const float4*)&params[rl][0];
        const float4 pB = *(const float4*)&params[rl][4];
        const float  hc = params[rl][8];
        const float px = pA.x, py = pA.y, tvs = pA.z, tvc = pA.w;
        const float tc = pB.x, ts = pB.y, ps  = pB.z, pp  = pB.w;
        float* rb = out + (size_t)(blockBase + rl) * OUTS;
        #pragma unroll
        for (int c = 0; c < 4; ++c) {
            const int j = c * 64 + lane;
            const float dx = px - ox[c];
            const float dy = py - oy[c];
            rb[2 + 2 * j] = dx * tvs - dy * tvc;
            rb[3 + 2 * j] = -(dx * tc + dy * ts);
            rb[516 + j]   = fmaf(ps, dx * tvc + dy * tvs,
                                 fmaf(pp, fmaf(dx, dx, dy * dy) - r2[c], hc));
        }
    }
}

extern "C" void kernel_launch(void* const* d_in, const int* in_sizes, int n_in,
                              void* d_out, int out_size, void* d_ws, size_t ws_size,
                              hipStream_t stream) {
    const float* x          = (const float*)d_in[0];
    const float* obstacles  = (const float*)d_in[1];
    const float* input_mean = (const float*)d_in[2];
    const float* input_std  = (const float*)d_in[3];
    const float* W1  = (const float*)d_in[4];
    const float* b1  = (const float*)d_in[5];
    const float* W21 = (const float*)d_in[6];
    const float* b21 = (const float*)d_in[7];
    const float* W22 = (const float*)d_in[8];
    const float* b22 = (const float*)d_in[9];
    const float* W31 = (const float*)d_in[10];
    const float* b31 = (const float*)d_in[11];
    const float* W32 = (const float*)d_in[12];
    const float* b32 = (const float*)d_in[13];

    float* out = (float*)d_out;
    const size_t ws_need = (size_t)NB_TOTAL * PSTRIDE * sizeof(float); // 4 MB

    if (ws_size >= ws_need) {
        float* ws = (float*)d_ws;
        k1_mlp<<<dim3(131072 / 256), dim3(256), 0, stream>>>(
            x, input_mean, input_std,
            W1, b1, W21, b21, W22, b22, W31, b31, W32, b32, ws);
        k2_fill<<<dim3(NB_TOTAL / 16), dim3(256), 0, stream>>>(obstacles, ws, out);
    } else {
        fused_kernel<<<dim3(NB_TOTAL / 64), dim3(256), 0, stream>>>(
            x, obstacles, input_mean, input_std,
            W1, b1, W21, b21, W22, b22, W31, b31, W32, b32, out);
    }
}

// Round 5
// 73.345 us; speedup vs baseline: 1.3322x; 1.3322x over previous
//
#include <hip/hip_runtime.h>
#include <math.h>

#define NB_TOTAL 65536
#define NOBS 256
#define OUTS 773            // 2 + 514 + 257
#define PSTRIDE 16          // floats per row in ws

typedef float f32x4 __attribute__((ext_vector_type(4)));
typedef float f32x2 __attribute__((ext_vector_type(2)));

// Output row layout (f32):
//  [0..1]    x31
//  [2+2j]    G_s[j][0], [3+2j] G_s[j][1]   j in 0..255   -> 2..513
//  [514,515] G_o
//  [516+j]   h_s[j]                                      -> 516..771
//  [772]     h_o
//
// ws row layout (16 f32) — rank-4 coefficients:
//  [0]A0 [1]tvs [2]tvc [3]A1 | [4]tc [5]ts [6]x31_0 [7]x31_1
//  [8]Go0 [9]Go1 | [10]ho [11]0 | [12]C [13]u [14]w [15]pp
// where:
//  G0(j) = A0 - tvs*ox + tvc*oy,  G1(j) = A1 + tc*ox + ts*oy
//  h(j)  = C + u*ox + w*oy + pp*q,  q = ox^2+oy^2-R^2

// ---------------------------------------------------------------------------
// K1: wave-pair per 64 rows. role0 -> x21/x31 branch + G coeffs;
//     role1 -> x22/x32 branch + h coeffs + ho.
// ---------------------------------------------------------------------------
__global__ __launch_bounds__(256) void k1_mlp(
    const float* __restrict__ x,
    const float* __restrict__ input_mean, const float* __restrict__ input_std,
    const float* __restrict__ W1,  const float* __restrict__ b1,
    const float* __restrict__ W21, const float* __restrict__ b21,
    const float* __restrict__ W22, const float* __restrict__ b22,
    const float* __restrict__ W31, const float* __restrict__ b31,
    const float* __restrict__ W32, const float* __restrict__ b32,
    float* __restrict__ ws)
{
    const int gt   = blockIdx.x * 256 + threadIdx.x;     // 0..131071
    const int lane = gt & 63;
    int role = (gt >> 6) & 1;
    role = __builtin_amdgcn_readfirstlane(role);          // wave-uniform
    const int row  = ((gt >> 7) << 6) | lane;             // each row hit by both roles

    float xr[8];
    {
        const float4 xa = *(const float4*)(x + (size_t)row * 8);
        const float4 xb = *(const float4*)(x + (size_t)row * 8 + 4);
        xr[0]=xa.x; xr[1]=xa.y; xr[2]=xa.z; xr[3]=xa.w;
        xr[4]=xb.x; xr[5]=xb.y; xr[6]=xb.z; xr[7]=xb.w;
    }

    const float* Wh = role ? W22 : W21;
    const float* bh = role ? b22 : b21;
    const float* Wo = role ? W32 : W31;
    const float* bo = role ? b32 : b31;

    float acc[32];
    #pragma unroll
    for (int k = 0; k < 32; ++k) acc[k] = bh[k];

    #pragma unroll 1
    for (int i0 = 0; i0 < 128; i0 += 8) {
        float hh[8];
        #pragma unroll
        for (int u = 0; u < 8; ++u) {
            float a = b1[i0 + u];
            #pragma unroll
            for (int k = 0; k < 8; ++k)
                a = fmaf(xr[k], W1[k * 128 + i0 + u], a);
            hh[u] = fmaxf(a, 0.0f);
        }
        #pragma unroll
        for (int u = 0; u < 8; ++u) {
            #pragma unroll
            for (int k = 0; k < 32; ++k)
                acc[k] = fmaf(hh[u], Wh[(i0 + u) * 32 + k], acc[k]);
        }
    }
    float o0 = bo[0], o1 = bo[1];
    #pragma unroll
    for (int k = 0; k < 32; ++k) {
        float a = fmaxf(acc[k], 0.0f);
        o0 = fmaf(a, Wo[k * 2 + 0], o0);
        o1 = fmaf(a, Wo[k * 2 + 1], o1);
    }

    // ---- dynamics (both roles, cheap) ----
    float x0v[8];
    #pragma unroll
    for (int k = 0; k < 8; ++k)
        x0v[k] = fmaf(xr[k], input_std[k], input_mean[k]);
    const float px = x0v[0], py = x0v[1], th = x0v[2], v = x0v[3];
    const float opx = x0v[4], opy = x0v[5], oth = x0v[6], ov = x0v[7];

    float st, ct, sto, cto;
    sincosf(th,  &st,  &ct);
    sincosf(oth, &sto, &cto);

    const float tvs = 2.0f * v * st;
    const float tvc = 2.0f * v * ct;
    const float tc  = 2.0f * ct;
    const float ts  = 2.0f * st;
    const float hc  = 2.0f * v * v;

    const float dxo = px - opx, dyo = py - opy;

    float* wp = ws + (size_t)row * PSTRIDE;

    if (role == 0) {
        const float A0  = px * tvs - py * tvc;
        const float A1  = -(px * tc + py * ts);
        const float Go0 = dxo * tvs - dyo * tvc;
        const float Go1 = -(dxo * tc + dyo * ts);
        *(float4*)(wp + 0) = make_float4(A0, tvs, tvc, A1);
        *(float4*)(wp + 4) = make_float4(tc, ts, o0, o1);
        *(f32x2*)(wp + 8)  = (f32x2){Go0, Go1};
    } else {
        const float p0 = 4.0f / (1.0f + __expf(-o0));
        const float p1 = 4.0f / (1.0f + __expf(-o1));
        const float ps = p0 + p1;
        const float pp = p0 * p1;
        // h coefficients
        const float B0 = px * tvc + py * tvs;
        const float C  = hc + ps * B0 + pp * (px * px + py * py);
        const float u  = -(ps * tvc) - 2.0f * pp * px;
        const float w  = -(ps * tvs) - 2.0f * pp * py;
        // opponent barrier
        const float ob  = dxo * dxo + dyo * dyo - 1.21f;     // Ro^2 = 1.1^2
        const float rvx = v * ct - ov * cto;
        const float rvy = v * st - ov * sto;
        const float obd = 2.0f * (dxo * rvx + dyo * rvy);
        const float cth_sum = ct * cto - st * sto;            // cos(th + oth)
        const float oLf2b = 2.0f * (v * v + ov * ov - 2.0f * v * ov * cth_sum);
        const float ho = oLf2b + ps * obd + pp * ob;
        *(f32x2*)(wp + 10)  = (f32x2){ho, 0.0f};
        *(float4*)(wp + 12) = make_float4(C, u, w, pp);
    }
}

// ---------------------------------------------------------------------------
// K2: one wave per row. Rank-4 evaluation with register-resident obstacle
// features -> per-wave LDS row buffer at alignment phase -> dense aligned
// dwordx4 streaming copy to out. No barriers, no bank conflicts.
// ---------------------------------------------------------------------------
__global__ __launch_bounds__(256, 8) void k2_fill(
    const float* __restrict__ obstacles,
    const float* __restrict__ ws,
    float* __restrict__ out)
{
    __shared__ float buf[4][776];                 // 776 dwords = 773 + max pad
    const int tid = threadIdx.x;
    const int l   = tid & 63;
    const int wv  = __builtin_amdgcn_readfirstlane(tid >> 6);
    float* wbuf = buf[wv];

    // G features: lane l handles flat G index i = c*64 + l, obstacle i>>1.
    // Even lane -> G0, odd lane -> G1; obstacle jg = c*32 + (l>>1).
    float gx[8], gy[8];
    {
        const int jg = l >> 1;
        #pragma unroll
        for (int c = 0; c < 8; ++c) {
            const float* o = obstacles + (size_t)(c * 32 + jg) * 3;
            gx[c] = o[0]; gy[c] = o[1];
        }
    }
    // h features: lane l handles obstacle jh = c*64 + l.
    float hx[4], hy[4], hq[4];
    #pragma unroll
    for (int c = 0; c < 4; ++c) {
        const float* o = obstacles + (size_t)(c * 64 + l) * 3;
        const float a = o[0], b = o[1], r = o[2] + 0.6f;   // R = 0.5 + rad + 0.1
        hx[c] = a; hy[c] = b; hq[c] = fmaf(a, a, b * b) - r * r;
    }

    const bool g0lane = ((l & 1) == 0);

    #pragma unroll 1
    for (int rr = 0; rr < 8; ++rr) {
        const int row = (blockIdx.x * 4 + wv) * 8 + rr;    // wave-uniform
        const float* cw = ws + (size_t)row * PSTRIDE;      // uniform -> s_load
        const float A0 = cw[0],  tvs = cw[1], tvc = cw[2], A1 = cw[3];
        const float tc = cw[4],  ts  = cw[5], x31_0 = cw[6], x31_1 = cw[7];
        const float Go0 = cw[8], Go1 = cw[9], ho = cw[10];
        const float C = cw[12],  u = cw[13],  w = cw[14],  pp = cw[15];

        const unsigned base = (unsigned)row * 773u;
        const int ph = (int)(base & 3u);                   // alignment phase

        // ---- compute into LDS (consecutive-lane addresses, conflict-free) --
        #pragma unroll
        for (int c = 0; c < 8; ++c) {
            const float ox = gx[c], oy = gy[c];
            const float val = g0lane ? fmaf(oy, tvc, fmaf(-ox, tvs, A0))
                                     : fmaf(oy, ts,  fmaf( ox, tc,  A1));
            wbuf[ph + 2 + c * 64 + l] = val;
        }
        #pragma unroll
        for (int c = 0; c < 4; ++c) {
            wbuf[ph + 516 + c * 64 + l] =
                fmaf(pp, hq[c], fmaf(w, hy[c], fmaf(u, hx[c], C)));
        }
        if (l == 0)      { wbuf[ph + 0]   = x31_0; wbuf[ph + 1]   = x31_1; }
        else if (l == 1) { wbuf[ph + 514] = Go0;   wbuf[ph + 515] = Go1;   }
        else if (l == 2) { wbuf[ph + 772] = ho; }

        // ---- stream LDS -> global: 194 aligned 16B chunks -------------------
        float* rowout = out + (base & ~3u);
        #pragma unroll
        for (int q = 0; q < 4; ++q) {
            const int c16 = q * 64 + l;
            if (c16 < 194) {
                const f32x4 v = *(const f32x4*)&wbuf[4 * c16];
                float* p = rowout + 4 * c16;
                const bool headP = (c16 == 0)   && (ph != 0);
                const bool tailP = (c16 == 193) && (ph != 3);
                if (!headP && !tailP) {
                    *(f32x4*)p = v;                          // full 16B chunk
                } else if (headP) {
                    // own dwords ph..3 (lower ones belong to previous row)
                    if (ph == 1)      { p[1] = v.y; *(f32x2*)(p + 2) = (f32x2){v.z, v.w}; }
                    else if (ph == 2) { *(f32x2*)(p + 2) = (f32x2){v.z, v.w}; }
                    else              { p[3] = v.w; }
                } else {
                    // own dwords 0..ph (upper ones belong to next row)
                    if (ph == 0)      { p[0] = v.x; }
                    else if (ph == 1) { *(f32x2*)p = (f32x2){v.x, v.y}; }
                    else              { *(f32x2*)p = (f32x2){v.x, v.y}; p[2] = v.z; }
                }
            }
        }
    }
}

// ---------------------------------------------------------------------------
// Fallback: fused single kernel (used only if ws too small)
// ---------------------------------------------------------------------------
__device__ __forceinline__ void mlp_dynamics(
    int row,
    const float* __restrict__ x,
    const float* __restrict__ input_mean, const float* __restrict__ input_std,
    const float* __restrict__ W1,  const float* __restrict__ b1,
    const float* __restrict__ W21, const float* __restrict__ b21,
    const float* __restrict__ W22, const float* __restrict__ b22,
    const float* __restrict__ W31, const float* __restrict__ b31,
    const float* __restrict__ W32, const float* __restrict__ b32,
    float* p /*16 floats out*/)
{
    float xr[8];
    {
        const float4 xa = *(const float4*)(x + (size_t)row * 8);
        const float4 xb = *(const float4*)(x + (size_t)row * 8 + 4);
        xr[0]=xa.x; xr[1]=xa.y; xr[2]=xa.z; xr[3]=xa.w;
        xr[4]=xb.x; xr[5]=xb.y; xr[6]=xb.z; xr[7]=xb.w;
    }
    float acc[32];
    #pragma unroll
    for (int k = 0; k < 32; ++k) acc[k] = b21[k];
    #pragma unroll 1
    for (int i0 = 0; i0 < 128; i0 += 8) {
        float hh[8];
        #pragma unroll
        for (int u = 0; u < 8; ++u) {
            float a = b1[i0 + u];
            #pragma unroll
            for (int k = 0; k < 8; ++k)
                a = fmaf(xr[k], W1[k * 128 + i0 + u], a);
            hh[u] = fmaxf(a, 0.0f);
        }
        #pragma unroll
        for (int u = 0; u < 8; ++u)
            #pragma unroll
            for (int k = 0; k < 32; ++k)
                acc[k] = fmaf(hh[u], W21[(i0 + u) * 32 + k], acc[k]);
    }
    float x31_0 = b31[0], x31_1 = b31[1];
    #pragma unroll
    for (int k = 0; k < 32; ++k) {
        float a21 = fmaxf(acc[k], 0.0f);
        x31_0 = fmaf(a21, W31[k * 2 + 0], x31_0);
        x31_1 = fmaf(a21, W31[k * 2 + 1], x31_1);
    }
    #pragma unroll
    for (int k = 0; k < 32; ++k) acc[k] = b22[k];
    #pragma unroll 1
    for (int i0 = 0; i0 < 128; i0 += 8) {
        float hh[8];
        #pragma unroll
        for (int u = 0; u < 8; ++u) {
            float a = b1[i0 + u];
            #pragma unroll
            for (int k = 0; k < 8; ++k)
                a = fmaf(xr[k], W1[k * 128 + i0 + u], a);
            hh[u] = fmaxf(a, 0.0f);
        }
        #pragma unroll
        for (int u = 0; u < 8; ++u)
            #pragma unroll
            for (int k = 0; k < 32; ++k)
                acc[k] = fmaf(hh[u], W22[(i0 + u) * 32 + k], acc[k]);
    }
    float z0 = b32[0], z1 = b32[1];
    #pragma unroll
    for (int k = 0; k < 32; ++k) {
        float a22 = fmaxf(acc[k], 0.0f);
        z0 = fmaf(a22, W32[k * 2 + 0], z0);
        z1 = fmaf(a22, W32[k * 2 + 1], z1);
    }
    const float p0 = 4.0f / (1.0f + __expf(-z0));
    const float p1 = 4.0f / (1.0f + __expf(-z1));
    float x0v[8];
    #pragma unroll
    for (int k = 0; k < 8; ++k)
        x0v[k] = fmaf(xr[k], input_std[k], input_mean[k]);
    const float px = x0v[0], py = x0v[1], th = x0v[2], v = x0v[3];
    const float opx = x0v[4], opy = x0v[5], oth = x0v[6], ov = x0v[7];
    float st, ct, sto, cto;
    sincosf(th,  &st,  &ct);
    sincosf(oth, &sto, &cto);
    const float ps  = p0 + p1;
    const float pp  = p0 * p1;
    const float tvs = 2.0f * v * st;
    const float tvc = 2.0f * v * ct;
    const float tc  = 2.0f * ct;
    const float ts  = 2.0f * st;
    const float hc  = 2.0f * v * v;
    const float dxo = px - opx, dyo = py - opy;
    const float ob  = dxo * dxo + dyo * dyo - 1.21f;
    const float rvx = v * ct - ov * cto;
    const float rvy = v * st - ov * sto;
    const float obd = 2.0f * (dxo * rvx + dyo * rvy);
    const float cth_sum = ct * cto - st * sto;
    const float oLf2b = 2.0f * (v * v + ov * ov - 2.0f * v * ov * cth_sum);
    const float Go0 = dxo * tvs - dyo * tvc;
    const float Go1 = -(dxo * tc + dyo * ts);
    const float hov = oLf2b + ps * obd + pp * ob;
    p[0]=px;  p[1]=py;  p[2]=tvs; p[3]=tvc;
    p[4]=tc;  p[5]=ts;  p[6]=ps;  p[7]=pp;
    p[8]=hc;  p[9]=x31_0; p[10]=x31_1; p[11]=Go0;
    p[12]=Go1; p[13]=hov; p[14]=0.0f; p[15]=0.0f;
}

__global__ __launch_bounds__(256, 4) void fused_kernel(
    const float* __restrict__ x,
    const float* __restrict__ obstacles,
    const float* __restrict__ input_mean, const float* __restrict__ input_std,
    const float* __restrict__ W1,  const float* __restrict__ b1,
    const float* __restrict__ W21, const float* __restrict__ b21,
    const float* __restrict__ W22, const float* __restrict__ b22,
    const float* __restrict__ W31, const float* __restrict__ b31,
    const float* __restrict__ W32, const float* __restrict__ b32,
    float* __restrict__ out)
{
    __shared__ float params[64][16];
    const int tid = threadIdx.x;
    const int blockBase = blockIdx.x * 64;

    if (tid < 64) {
        const int row = blockBase + tid;
        float p[16];
        mlp_dynamics(row, x, input_mean, input_std,
                     W1, b1, W21, b21, W22, b22, W31, b31, W32, b32, p);
        float* rb = out + (size_t)row * OUTS;
        rb[0] = p[9]; rb[1] = p[10]; rb[514] = p[11]; rb[515] = p[12]; rb[772] = p[13];
        #pragma unroll
        for (int k = 0; k < 16; ++k) params[tid][k] = p[k];
    }
    __syncthreads();

    const int lane = tid & 63;
    const int wave = tid >> 6;
    float ox[4], oy[4], r2[4];
    #pragma unroll
    for (int c = 0; c < 4; ++c) {
        const float* o = obstacles + (size_t)(c * 64 + lane) * 3;
        const float a = o[0], b = o[1], r = o[2] + 0.6f;
        ox[c] = a; oy[c] = b; r2[c] = r * r;
    }
    #pragma unroll 1
    for (int rr = 0; rr < 16; ++rr) {
        const int rl = wave * 16 + rr;
        const float4 pA = *(const float4*)&params[rl][0];
        const float4 pB = *(const float4*)&params[rl][4];
        const float  hc = params[rl][8];
        const float px = pA.x, py = pA.y, tvs = pA.z, tvc = pA.w;
        const float tc = pB.x, ts = pB.y, ps  = pB.z, pp  = pB.w;
        float* rb = out + (size_t)(blockBase + rl) * OUTS;
        #pragma unroll
        for (int c = 0; c < 4; ++c) {
            const int j = c * 64 + lane;
            const float dx = px - ox[c];
            const float dy = py - oy[c];
            rb[2 + 2 * j] = dx * tvs - dy * tvc;
            rb[3 + 2 * j] = -(dx * tc + dy * ts);
            rb[516 + j]   = fmaf(ps, dx * tvc + dy * tvs,
                                 fmaf(pp, fmaf(dx, dx, dy * dy) - r2[c], hc));
        }
    }
}

extern "C" void kernel_launch(void* const* d_in, const int* in_sizes, int n_in,
                              void* d_out, int out_size, void* d_ws, size_t ws_size,
                              hipStream_t stream) {
    const float* x          = (const float*)d_in[0];
    const float* obstacles  = (const float*)d_in[1];
    const float* input_mean = (const float*)d_in[2];
    const float* input_std  = (const float*)d_in[3];
    const float* W1  = (const float*)d_in[4];
    const float* b1  = (const float*)d_in[5];
    const float* W21 = (const float*)d_in[6];
    const float* b21 = (const float*)d_in[7];
    const float* W22 = (const float*)d_in[8];
    const float* b22 = (const float*)d_in[9];
    const float* W31 = (const float*)d_in[10];
    const float* b31 = (const float*)d_in[11];
    const float* W32 = (const float*)d_in[12];
    const float* b32 = (const float*)d_in[13];

    float* out = (float*)d_out;
    const size_t ws_need = (size_t)NB_TOTAL * PSTRIDE * sizeof(float); // 4 MB

    if (ws_size >= ws_need) {
        float* ws = (float*)d_ws;
        k1_mlp<<<dim3(131072 / 256), dim3(256), 0, stream>>>(
            x, input_mean, input_std,
            W1, b1, W21, b21, W22, b22, W31, b31, W32, b32, ws);
        // 2048 blocks x 4 waves x 8 rows = 65536 rows; 8 blocks/CU
        k2_fill<<<dim3(NB_TOTAL / 32), dim3(256), 0, stream>>>(obstacles, ws, out);
    } else {
        fused_kernel<<<dim3(NB_TOTAL / 64), dim3(256), 0, stream>>>(
            x, obstacles, input_mean, input_std,
            W1, b1, W21, b21, W22, b22, W31, b31, W32, b32, out);
    }
}

// Round 6
// 57.456 us; speedup vs baseline: 1.7006x; 1.2765x over previous
//
#include <hip/hip_runtime.h>
#include <math.h>

#define NB_TOTAL 65536
#define NOBS 256
#define OUTS 773            // 2 + 514 + 257
#define PSTRIDE 16          // floats per row in ws

typedef float f32x4 __attribute__((ext_vector_type(4)));
typedef float f32x2 __attribute__((ext_vector_type(2)));

// Output row layout (f32):
//  [0..1]    x31
//  [2+2j]    G_s[j][0], [3+2j] G_s[j][1]   j in 0..255   -> 2..513
//  [514,515] G_o
//  [516+j]   h_s[j]                                      -> 516..771
//  [772]     h_o
//
// ws row layout (16 f32) — rank-4 coefficients:
//  [0]A0 [1]tvs [2]tvc [3]A1 | [4]tc [5]ts [6]x31_0 [7]x31_1
//  [8]Go0 [9]Go1 | [10]ho [11]0 | [12]C [13]u [14]w [15]pp
// where:
//  G0(j) = A0 - tvs*ox + tvc*oy,  G1(j) = A1 + tc*ox + ts*oy
//  h(j)  = C + u*ox + w*oy + pp*q,  q = ox^2+oy^2-R^2

// ---------------------------------------------------------------------------
// K1: 64 rows per block, 4 full waves = {role0,role1} x {hidden half 0,1}.
// Each wave computes a partial acc[32] over half the hidden layer; halves
// combined via LDS. Doubles wave count (4/SIMD) and halves each wave's
// SMEM-latency chain vs the monolithic version.
// ---------------------------------------------------------------------------
__global__ __launch_bounds__(256) void k1_mlp(
    const float* __restrict__ x,
    const float* __restrict__ input_mean, const float* __restrict__ input_std,
    const float* __restrict__ W1,  const float* __restrict__ b1,
    const float* __restrict__ W21, const float* __restrict__ b21,
    const float* __restrict__ W22, const float* __restrict__ b22,
    const float* __restrict__ W31, const float* __restrict__ b31,
    const float* __restrict__ W32, const float* __restrict__ b32,
    float* __restrict__ ws)
{
    __shared__ float pacc[2][64][33];     // [role][row][k], +1 pad (stride 33)

    const int tid  = threadIdx.x;
    const int l    = tid & 63;
    const int wv   = __builtin_amdgcn_readfirstlane(tid >> 6);
    const int role = wv & 1;
    const int half = wv >> 1;
    const int row  = blockIdx.x * 64 + l;

    float xr[8];
    {
        const float4 xa = *(const float4*)(x + (size_t)row * 8);
        const float4 xb = *(const float4*)(x + (size_t)row * 8 + 4);
        xr[0]=xa.x; xr[1]=xa.y; xr[2]=xa.z; xr[3]=xa.w;
        xr[4]=xb.x; xr[5]=xb.y; xr[6]=xb.z; xr[7]=xb.w;
    }

    const float* Wh = role ? W22 : W21;
    const float* bh = role ? b22 : b21;

    float acc[32];
    #pragma unroll
    for (int k = 0; k < 32; ++k) acc[k] = half ? 0.0f : bh[k];

    const int ibeg = half * 64;
    #pragma unroll 1
    for (int i0 = ibeg; i0 < ibeg + 64; i0 += 8) {
        float hh[8];
        #pragma unroll
        for (int u = 0; u < 8; ++u) {
            float a = b1[i0 + u];
            #pragma unroll
            for (int k = 0; k < 8; ++k)
                a = fmaf(xr[k], W1[k * 128 + i0 + u], a);
            hh[u] = fmaxf(a, 0.0f);
        }
        #pragma unroll
        for (int u = 0; u < 8; ++u) {
            #pragma unroll
            for (int k = 0; k < 32; ++k)
                acc[k] = fmaf(hh[u], Wh[(i0 + u) * 32 + k], acc[k]);
        }
    }

    if (half == 0) {
        #pragma unroll
        for (int k = 0; k < 32; ++k) pacc[role][l][k] = acc[k];
    }
    __syncthreads();

    if (half == 1) {
        #pragma unroll
        for (int k = 0; k < 32; ++k) acc[k] += pacc[role][l][k];

        const float* Wo = role ? W32 : W31;
        const float* bo = role ? b32 : b31;
        float o0 = bo[0], o1 = bo[1];
        #pragma unroll
        for (int k = 0; k < 32; ++k) {
            float a = fmaxf(acc[k], 0.0f);
            o0 = fmaf(a, Wo[k * 2 + 0], o0);
            o1 = fmaf(a, Wo[k * 2 + 1], o1);
        }

        // ---- dynamics ----
        float x0v[8];
        #pragma unroll
        for (int k = 0; k < 8; ++k)
            x0v[k] = fmaf(xr[k], input_std[k], input_mean[k]);
        const float px = x0v[0], py = x0v[1], th = x0v[2], v = x0v[3];
        const float opx = x0v[4], opy = x0v[5], oth = x0v[6], ov = x0v[7];

        float st, ct, sto, cto;
        sincosf(th,  &st,  &ct);
        sincosf(oth, &sto, &cto);

        const float tvs = 2.0f * v * st;
        const float tvc = 2.0f * v * ct;
        const float tc  = 2.0f * ct;
        const float ts  = 2.0f * st;
        const float hc  = 2.0f * v * v;

        const float dxo = px - opx, dyo = py - opy;

        float* wp = ws + (size_t)row * PSTRIDE;

        if (role == 0) {
            const float A0  = px * tvs - py * tvc;
            const float A1  = -(px * tc + py * ts);
            const float Go0 = dxo * tvs - dyo * tvc;
            const float Go1 = -(dxo * tc + dyo * ts);
            *(float4*)(wp + 0) = make_float4(A0, tvs, tvc, A1);
            *(float4*)(wp + 4) = make_float4(tc, ts, o0, o1);
            *(f32x2*)(wp + 8)  = (f32x2){Go0, Go1};
        } else {
            const float p0 = 4.0f / (1.0f + __expf(-o0));
            const float p1 = 4.0f / (1.0f + __expf(-o1));
            const float ps = p0 + p1;
            const float pp = p0 * p1;
            const float B0 = px * tvc + py * tvs;
            const float C  = hc + ps * B0 + pp * (px * px + py * py);
            const float u  = -(ps * tvc) - 2.0f * pp * px;
            const float w  = -(ps * tvs) - 2.0f * pp * py;
            const float ob  = dxo * dxo + dyo * dyo - 1.21f;     // Ro^2 = 1.1^2
            const float rvx = v * ct - ov * cto;
            const float rvy = v * st - ov * sto;
            const float obd = 2.0f * (dxo * rvx + dyo * rvy);
            const float cth_sum = ct * cto - st * sto;            // cos(th + oth)
            const float oLf2b = 2.0f * (v * v + ov * ov - 2.0f * v * ov * cth_sum);
            const float ho = oLf2b + ps * obd + pp * ob;
            *(f32x2*)(wp + 10)  = (f32x2){ho, 0.0f};
            *(float4*)(wp + 12) = make_float4(C, u, w, pp);
        }
    }
}

// ---------------------------------------------------------------------------
// K2: 32 rows per block (4 waves x 8 rows). Coefficients block-staged into
// LDS once (no per-row s_load chain). Per row: rank-4 eval with register
// obstacle features -> LDS row buffer at alignment phase -> branchless
// aligned dwordx4 copy (chunks 1..192), head/tail by lanes 0/1.
// ---------------------------------------------------------------------------
__global__ __launch_bounds__(256, 8) void k2_fill(
    const float* __restrict__ obstacles,
    const float* __restrict__ ws,
    float* __restrict__ out)
{
    __shared__ float buf[4][776];
    __shared__ float cf[32][16];

    const int tid = threadIdx.x;
    const int l   = tid & 63;
    const int wv  = __builtin_amdgcn_readfirstlane(tid >> 6);
    float* wbuf = buf[wv];

    // ---- stage this block's 32 rows of coefficients (coalesced, 2 KB) -----
    {
        const int r2  = tid >> 3;            // 0..31
        const int k2i = (tid & 7) * 2;       // 0,2,..,14
        const f32x2 v = *(const f32x2*)(ws +
            ((size_t)(blockIdx.x * 32 + r2)) * PSTRIDE + k2i);
        *(f32x2*)&cf[r2][k2i] = v;
    }

    // ---- obstacle features in registers -----------------------------------
    // G: lane l handles flat G index i = c*64 + l (c=0..7): obstacle i>>1.
    float gx[8], gy[8];
    {
        const int jg = l >> 1;
        #pragma unroll
        for (int c = 0; c < 8; ++c) {
            const float* o = obstacles + (size_t)(c * 32 + jg) * 3;
            gx[c] = o[0]; gy[c] = o[1];
        }
    }
    // h: lane l handles obstacle jh = c*64 + l (c=0..3).
    float hx[4], hy[4], hq[4];
    #pragma unroll
    for (int c = 0; c < 4; ++c) {
        const float* o = obstacles + (size_t)(c * 64 + l) * 3;
        const float a = o[0], b = o[1], r = o[2] + 0.6f;   // R = 0.5 + rad + 0.1
        hx[c] = a; hy[c] = b; hq[c] = fmaf(a, a, b * b) - r * r;
    }

    __syncthreads();

    const bool g0lane = ((l & 1) == 0);

    #pragma unroll 1
    for (int rr = 0; rr < 8; ++rr) {
        const int rloc = wv * 8 + rr;
        const int row  = blockIdx.x * 32 + rloc;

        const f32x4 c0 = *(const f32x4*)&cf[rloc][0];   // A0,tvs,tvc,A1
        const f32x4 c1 = *(const f32x4*)&cf[rloc][4];   // tc,ts,x31_0,x31_1
        const f32x4 c2 = *(const f32x4*)&cf[rloc][8];   // Go0,Go1,ho,-
        const f32x4 c3 = *(const f32x4*)&cf[rloc][12];  // C,u,w,pp
        const float A0 = c0.x, tvs = c0.y, tvc = c0.z, A1 = c0.w;
        const float tc = c1.x, ts  = c1.y, x31_0 = c1.z, x31_1 = c1.w;
        const float Go0 = c2.x, Go1 = c2.y, ho = c2.z;
        const float C = c3.x, u = c3.y, w = c3.z, pp = c3.w;

        const unsigned base = (unsigned)row * 773u;
        const int ph = (int)(base & 3u);                   // alignment phase
        float* a0p = out + (base & ~3u);

        // ---- compute into LDS (consecutive lanes, conflict-free) ----------
        #pragma unroll
        for (int c = 0; c < 8; ++c) {
            const float ox = gx[c], oy = gy[c];
            const float val = g0lane ? fmaf(oy, tvc, fmaf(-ox, tvs, A0))
                                     : fmaf(oy, ts,  fmaf( ox, tc,  A1));
            wbuf[ph + 2 + c * 64 + l] = val;
        }
        #pragma unroll
        for (int c = 0; c < 4; ++c) {
            wbuf[ph + 516 + c * 64 + l] =
                fmaf(pp, hq[c], fmaf(w, hy[c], fmaf(u, hx[c], C)));
        }
        if (l == 0)      { wbuf[ph + 0]   = x31_0; wbuf[ph + 1]   = x31_1; }
        else if (l == 1) { wbuf[ph + 514] = Go0;   wbuf[ph + 515] = Go1;   }
        else if (l == 2) { wbuf[ph + 772] = ho; }

        // ---- copy: full chunks 1..192, branchless -------------------------
        #pragma unroll
        for (int q = 0; q < 3; ++q) {
            const int c16 = q * 64 + l + 1;                // 1..192
            *(f32x4*)(a0p + 4 * c16) = *(const f32x4*)&wbuf[4 * c16];
        }

        // ---- head (lane 0) / tail (lane 1) --------------------------------
        if (l == 0) {
            float* p = out + base;
            if (ph == 0) {
                *(f32x4*)p = *(const f32x4*)&wbuf[0];
            } else if (ph == 1) {
                p[0] = wbuf[1];
                *(f32x2*)(p + 1) = (f32x2){wbuf[2], wbuf[3]};
            } else if (ph == 2) {
                *(f32x2*)p = (f32x2){wbuf[2], wbuf[3]};
            } else {
                p[0] = wbuf[3];
            }
        } else if (l == 1) {
            float* p = a0p + 772;                          // 16B-aligned
            if (ph == 0) {
                p[0] = wbuf[772];
            } else if (ph == 1) {
                *(f32x2*)p = (f32x2){wbuf[772], wbuf[773]};
            } else if (ph == 2) {
                *(f32x2*)p = (f32x2){wbuf[772], wbuf[773]};
                p[2] = wbuf[774];
            } else {
                *(f32x4*)p = *(const f32x4*)&wbuf[772];
            }
        }
    }
}

// ---------------------------------------------------------------------------
// Fallback: fused single kernel (used only if ws too small)
// ---------------------------------------------------------------------------
__device__ __forceinline__ void mlp_dynamics(
    int row,
    const float* __restrict__ x,
    const float* __restrict__ input_mean, const float* __restrict__ input_std,
    const float* __restrict__ W1,  const float* __restrict__ b1,
    const float* __restrict__ W21, const float* __restrict__ b21,
    const float* __restrict__ W22, const float* __restrict__ b22,
    const float* __restrict__ W31, const float* __restrict__ b31,
    const float* __restrict__ W32, const float* __restrict__ b32,
    float* p /*16 floats out*/)
{
    float xr[8];
    {
        const float4 xa = *(const float4*)(x + (size_t)row * 8);
        const float4 xb = *(const float4*)(x + (size_t)row * 8 + 4);
        xr[0]=xa.x; xr[1]=xa.y; xr[2]=xa.z; xr[3]=xa.w;
        xr[4]=xb.x; xr[5]=xb.y; xr[6]=xb.z; xr[7]=xb.w;
    }
    float acc[32];
    #pragma unroll
    for (int k = 0; k < 32; ++k) acc[k] = b21[k];
    #pragma unroll 1
    for (int i0 = 0; i0 < 128; i0 += 8) {
        float hh[8];
        #pragma unroll
        for (int u = 0; u < 8; ++u) {
            float a = b1[i0 + u];
            #pragma unroll
            for (int k = 0; k < 8; ++k)
                a = fmaf(xr[k], W1[k * 128 + i0 + u], a);
            hh[u] = fmaxf(a, 0.0f);
        }
        #pragma unroll
        for (int u = 0; u < 8; ++u)
            #pragma unroll
            for (int k = 0; k < 32; ++k)
                acc[k] = fmaf(hh[u], W21[(i0 + u) * 32 + k], acc[k]);
    }
    float x31_0 = b31[0], x31_1 = b31[1];
    #pragma unroll
    for (int k = 0; k < 32; ++k) {
        float a21 = fmaxf(acc[k], 0.0f);
        x31_0 = fmaf(a21, W31[k * 2 + 0], x31_0);
        x31_1 = fmaf(a21, W31[k * 2 + 1], x31_1);
    }
    #pragma unroll
    for (int k = 0; k < 32; ++k) acc[k] = b22[k];
    #pragma unroll 1
    for (int i0 = 0; i0 < 128; i0 += 8) {
        float hh[8];
        #pragma unroll
        for (int u = 0; u < 8; ++u) {
            float a = b1[i0 + u];
            #pragma unroll
            for (int k = 0; k < 8; ++k)
                a = fmaf(xr[k], W1[k * 128 + i0 + u], a);
            hh[u] = fmaxf(a, 0.0f);
        }
        #pragma unroll
        for (int u = 0; u < 8; ++u)
            #pragma unroll
            for (int k = 0; k < 32; ++k)
                acc[k] = fmaf(hh[u], W22[(i0 + u) * 32 + k], acc[k]);
    }
    float z0 = b32[0], z1 = b32[1];
    #pragma unroll
    for (int k = 0; k < 32; ++k) {
        float a22 = fmaxf(acc[k], 0.0f);
        z0 = fmaf(a22, W32[k * 2 + 0], z0);
        z1 = fmaf(a22, W32[k * 2 + 1], z1);
    }
    const float p0 = 4.0f / (1.0f + __expf(-z0));
    const float p1 = 4.0f / (1.0f + __expf(-z1));
    float x0v[8];
    #pragma unroll
    for (int k = 0; k < 8; ++k)
        x0v[k] = fmaf(xr[k], input_std[k], input_mean[k]);
    const float px = x0v[0], py = x0v[1], th = x0v[2], v = x0v[3];
    const float opx = x0v[4], opy = x0v[5], oth = x0v[6], ov = x0v[7];
    float st, ct, sto, cto;
    sincosf(th,  &st,  &ct);
    sincosf(oth, &sto, &cto);
    const float ps  = p0 + p1;
    const float pp  = p0 * p1;
    const float tvs = 2.0f * v * st;
    const float tvc = 2.0f * v * ct;
    const float tc  = 2.0f * ct;
    const float ts  = 2.0f * st;
    const float hc  = 2.0f * v * v;
    const float dxo = px - opx, dyo = py - opy;
    const float ob  = dxo * dxo + dyo * dyo - 1.21f;
    const float rvx = v * ct - ov * cto;
    const float rvy = v * st - ov * sto;
    const float obd = 2.0f * (dxo * rvx + dyo * rvy);
    const float cth_sum = ct * cto - st * sto;
    const float oLf2b = 2.0f * (v * v + ov * ov - 2.0f * v * ov * cth_sum);
    const float Go0 = dxo * tvs - dyo * tvc;
    const float Go1 = -(dxo * tc + dyo * ts);
    const float hov = oLf2b + ps * obd + pp * ob;
    p[0]=px;  p[1]=py;  p[2]=tvs; p[3]=tvc;
    p[4]=tc;  p[5]=ts;  p[6]=ps;  p[7]=pp;
    p[8]=hc;  p[9]=x31_0; p[10]=x31_1; p[11]=Go0;
    p[12]=Go1; p[13]=hov; p[14]=0.0f; p[15]=0.0f;
}

__global__ __launch_bounds__(256, 4) void fused_kernel(
    const float* __restrict__ x,
    const float* __restrict__ obstacles,
    const float* __restrict__ input_mean, const float* __restrict__ input_std,
    const float* __restrict__ W1,  const float* __restrict__ b1,
    const float* __restrict__ W21, const float* __restrict__ b21,
    const float* __restrict__ W22, const float* __restrict__ b22,
    const float* __restrict__ W31, const float* __restrict__ b31,
    const float* __restrict__ W32, const float* __restrict__ b32,
    float* __restrict__ out)
{
    __shared__ float params[64][16];
    const int tid = threadIdx.x;
    const int blockBase = blockIdx.x * 64;

    if (tid < 64) {
        const int row = blockBase + tid;
        float p[16];
        mlp_dynamics(row, x, input_mean, input_std,
                     W1, b1, W21, b21, W22, b22, W31, b31, W32, b32, p);
        float* rb = out + (size_t)row * OUTS;
        rb[0] = p[9]; rb[1] = p[10]; rb[514] = p[11]; rb[515] = p[12]; rb[772] = p[13];
        #pragma unroll
        for (int k = 0; k < 16; ++k) params[tid][k] = p[k];
    }
    __syncthreads();

    const int lane = tid & 63;
    const int wave = tid >> 6;
    float ox[4], oy[4], r2[4];
    #pragma unroll
    for (int c = 0; c < 4; ++c) {
        const float* o = obstacles + (size_t)(c * 64 + lane) * 3;
        const float a = o[0], b = o[1], r = o[2] + 0.6f;
        ox[c] = a; oy[c] = b; r2[c] = r * r;
    }
    #pragma unroll 1
    for (int rr = 0; rr < 16; ++rr) {
        const int rl = wave * 16 + rr;
        const float4 pA = *(const float4*)&params[rl][0];
        const float4 pB = *(const float4*)&params[rl][4];
        const float  hc = params[rl][8];
        const float px = pA.x, py = pA.y, tvs = pA.z, tvc = pA.w;
        const float tc = pB.x, ts = pB.y, ps  = pB.z, pp  = pB.w;
        float* rb = out + (size_t)(blockBase + rl) * OUTS;
        #pragma unroll
        for (int c = 0; c < 4; ++c) {
            const int j = c * 64 + lane;
            const float dx = px - ox[c];
            const float dy = py - oy[c];
            rb[2 + 2 * j] = dx * tvs - dy * tvc;
            rb[3 + 2 * j] = -(dx * tc + dy * ts);
            rb[516 + j]   = fmaf(ps, dx * tvc + dy * tvs,
                                 fmaf(pp, fmaf(dx, dx, dy * dy) - r2[c], hc));
        }
    }
}

extern "C" void kernel_launch(void* const* d_in, const int* in_sizes, int n_in,
                              void* d_out, int out_size, void* d_ws, size_t ws_size,
                              hipStream_t stream) {
    const float* x          = (const float*)d_in[0];
    const float* obstacles  = (const float*)d_in[1];
    const float* input_mean = (const float*)d_in[2];
    const float* input_std  = (const float*)d_in[3];
    const float* W1  = (const float*)d_in[4];
    const float* b1  = (const float*)d_in[5];
    const float* W21 = (const float*)d_in[6];
    const float* b21 = (const float*)d_in[7];
    const float* W22 = (const float*)d_in[8];
    const float* b22 = (const float*)d_in[9];
    const float* W31 = (const float*)d_in[10];
    const float* b31 = (const float*)d_in[11];
    const float* W32 = (const float*)d_in[12];
    const float* b32 = (const float*)d_in[13];

    float* out = (float*)d_out;
    const size_t ws_need = (size_t)NB_TOTAL * PSTRIDE * sizeof(float); // 4 MB

    if (ws_size >= ws_need) {
        float* ws = (float*)d_ws;
        // 1024 blocks x 4 waves, 64 rows/block (role x half split)
        k1_mlp<<<dim3(NB_TOTAL / 64), dim3(256), 0, stream>>>(
            x, input_mean, input_std,
            W1, b1, W21, b21, W22, b22, W31, b31, W32, b32, ws);
        // 2048 blocks x 4 waves x 8 rows = 65536 rows; 8 blocks/CU
        k2_fill<<<dim3(NB_TOTAL / 32), dim3(256), 0, stream>>>(obstacles, ws, out);
    } else {
        fused_kernel<<<dim3(NB_TOTAL / 64), dim3(256), 0, stream>>>(
            x, obstacles, input_mean, input_std,
            W1, b1, W21, b21, W22, b22, W31, b31, W32, b32, out);
    }
}

// Round 8
// 53.247 us; speedup vs baseline: 1.8351x; 1.0791x over previous
//
#include <hip/hip_runtime.h>
#include <math.h>

#define NB_TOTAL 65536
#define NOBS 256
#define OUTS 773            // 2 + 514 + 257

typedef float f32x4 __attribute__((ext_vector_type(4)));
typedef float f32x2 __attribute__((ext_vector_type(2)));

// Output row layout (f32):
//  [0..1]    x31
//  [2+2j]    G_s[j][0], [3+2j] G_s[j][1]   j in 0..255   -> 2..513
//  [514,515] G_o
//  [516+j]   h_s[j]                                      -> 516..771
//  [772]     h_o
//
// prm row layout (16 f32) — rank-4 coefficients (same as R6 ws layout):
//  [0]A0 [1]tvs [2]tvc [3]A1 | [4]tc [5]ts [6]x31_0 [7]x31_1
//  [8]Go0 [9]Go1 | [10]ho [11]0 | [12]C [13]u [14]w [15]pp
// where:
//  G0(j) = A0 - tvs*ox + tvc*oy,  G1(j) = A1 + tc*ox + ts*oy
//  h(j)  = C + u*ox + w*oy + pp*q,  q = ox^2+oy^2-R^2
//
// Fused kernel: 64 rows/block, 1024 blocks (4 blocks/CU, 16 waves/CU).
// Phase A = R6 k1 (role x half wave split), coefficients -> LDS prm.
// Phase B = R6 k2 (register obstacle features -> LDS row buffer at
// alignment phase -> aligned dwordx4 copy), 16 rows per wave.
// Lesson R7: misaligned global_store_dwordx4 is NOT safe on gfx950 —
// the LDS re-alignment staging here is the proven-correct mechanism.

__global__ __launch_bounds__(256) void fused2(
    const float* __restrict__ x,
    const float* __restrict__ obstacles,
    const float* __restrict__ input_mean, const float* __restrict__ input_std,
    const float* __restrict__ W1,  const float* __restrict__ b1,
    const float* __restrict__ W21, const float* __restrict__ b21,
    const float* __restrict__ W22, const float* __restrict__ b22,
    const float* __restrict__ W31, const float* __restrict__ b31,
    const float* __restrict__ W32, const float* __restrict__ b32,
    float* __restrict__ out)
{
    __shared__ float pacc[2][64][33];   // partial acc exchange (+1 pad)
    __shared__ float prm[64][16];       // per-row coefficients
    __shared__ float wbuf[4][776];      // per-wave row staging

    const int tid  = threadIdx.x;
    const int l    = tid & 63;
    const int wv   = __builtin_amdgcn_readfirstlane(tid >> 6);
    const int role = wv & 1;
    const int half = wv >> 1;
    const int row  = blockIdx.x * 64 + l;

    // ======================= Phase A: MLP + coefficients ====================
    float xr[8];
    {
        const float4 xa = *(const float4*)(x + (size_t)row * 8);
        const float4 xb = *(const float4*)(x + (size_t)row * 8 + 4);
        xr[0]=xa.x; xr[1]=xa.y; xr[2]=xa.z; xr[3]=xa.w;
        xr[4]=xb.x; xr[5]=xb.y; xr[6]=xb.z; xr[7]=xb.w;
    }

    const float* Wh = role ? W22 : W21;
    const float* bh = role ? b22 : b21;

    float acc[32];
    #pragma unroll
    for (int k = 0; k < 32; ++k) acc[k] = half ? 0.0f : bh[k];

    const int ibeg = half * 64;
    #pragma unroll 1
    for (int i0 = ibeg; i0 < ibeg + 64; i0 += 8) {
        float hh[8];
        #pragma unroll
        for (int u = 0; u < 8; ++u) {
            float a = b1[i0 + u];
            #pragma unroll
            for (int k = 0; k < 8; ++k)
                a = fmaf(xr[k], W1[k * 128 + i0 + u], a);
            hh[u] = fmaxf(a, 0.0f);
        }
        #pragma unroll
        for (int u = 0; u < 8; ++u) {
            #pragma unroll
            for (int k = 0; k < 32; ++k)
                acc[k] = fmaf(hh[u], Wh[(i0 + u) * 32 + k], acc[k]);
        }
    }

    if (half == 0) {
        #pragma unroll
        for (int k = 0; k < 32; ++k) pacc[role][l][k] = acc[k];
    }
    __syncthreads();

    if (half == 1) {
        #pragma unroll
        for (int k = 0; k < 32; ++k) acc[k] += pacc[role][l][k];

        const float* Wo = role ? W32 : W31;
        const float* bo = role ? b32 : b31;
        float o0 = bo[0], o1 = bo[1];
        #pragma unroll
        for (int k = 0; k < 32; ++k) {
            float a = fmaxf(acc[k], 0.0f);
            o0 = fmaf(a, Wo[k * 2 + 0], o0);
            o1 = fmaf(a, Wo[k * 2 + 1], o1);
        }

        float x0v[8];
        #pragma unroll
        for (int k = 0; k < 8; ++k)
            x0v[k] = fmaf(xr[k], input_std[k], input_mean[k]);
        const float px = x0v[0], py = x0v[1], th = x0v[2], v = x0v[3];
        const float opx = x0v[4], opy = x0v[5], oth = x0v[6], ov = x0v[7];

        float st, ct, sto, cto;
        sincosf(th,  &st,  &ct);
        sincosf(oth, &sto, &cto);

        const float tvs = 2.0f * v * st;
        const float tvc = 2.0f * v * ct;
        const float tc  = 2.0f * ct;
        const float ts  = 2.0f * st;
        const float hc  = 2.0f * v * v;

        const float dxo = px - opx, dyo = py - opy;

        if (role == 0) {
            const float A0  = px * tvs - py * tvc;
            const float A1  = -(px * tc + py * ts);
            const float Go0 = dxo * tvs - dyo * tvc;
            const float Go1 = -(dxo * tc + dyo * ts);
            *(f32x4*)&prm[l][0] = (f32x4){A0, tvs, tvc, A1};
            *(f32x4*)&prm[l][4] = (f32x4){tc, ts, o0, o1};
            *(f32x2*)&prm[l][8] = (f32x2){Go0, Go1};
        } else {
            const float p0 = 4.0f / (1.0f + __expf(-o0));
            const float p1 = 4.0f / (1.0f + __expf(-o1));
            const float ps = p0 + p1;
            const float pp = p0 * p1;
            const float B0 = px * tvc + py * tvs;
            const float C  = hc + ps * B0 + pp * (px * px + py * py);
            const float u  = -(ps * tvc) - 2.0f * pp * px;
            const float w  = -(ps * tvs) - 2.0f * pp * py;
            const float ob  = dxo * dxo + dyo * dyo - 1.21f;     // Ro^2 = 1.1^2
            const float rvx = v * ct - ov * cto;
            const float rvy = v * st - ov * sto;
            const float obd = 2.0f * (dxo * rvx + dyo * rvy);
            const float cth_sum = ct * cto - st * sto;            // cos(th+oth)
            const float oLf2b = 2.0f * (v * v + ov * ov - 2.0f * v * ov * cth_sum);
            const float ho = oLf2b + ps * obd + pp * ob;
            *(f32x2*)&prm[l][10]  = (f32x2){ho, 0.0f};
            *(f32x4*)&prm[l][12]  = (f32x4){C, u, w, pp};
        }
    }
    __syncthreads();

    // ======================= Phase B: barrier fill ==========================
    float* wb = wbuf[wv];

    // G features: lane l handles flat G index i = c*64 + l (c=0..7),
    // obstacle i>>1 = c*32 + (l>>1), component l&1.
    float gx[8], gy[8];
    {
        const int jg = l >> 1;
        #pragma unroll
        for (int c = 0; c < 8; ++c) {
            const float* o = obstacles + (size_t)(c * 32 + jg) * 3;
            gx[c] = o[0]; gy[c] = o[1];
        }
    }
    // h features: lane l handles obstacle jh = c*64 + l (c=0..3).
    float hx[4], hy[4], hq[4];
    #pragma unroll
    for (int c = 0; c < 4; ++c) {
        const float* o = obstacles + (size_t)(c * 64 + l) * 3;
        const float a = o[0], b = o[1], r = o[2] + 0.6f;   // R = 0.5 + rad + 0.1
        hx[c] = a; hy[c] = b; hq[c] = fmaf(a, a, b * b) - r * r;
    }

    const bool g0lane = ((l & 1) == 0);

    #pragma unroll 1
    for (int rr = 0; rr < 16; ++rr) {
        const int rloc = wv * 16 + rr;
        const int row2 = blockIdx.x * 64 + rloc;

        const f32x4 c0 = *(const f32x4*)&prm[rloc][0];   // A0,tvs,tvc,A1
        const f32x4 c1 = *(const f32x4*)&prm[rloc][4];   // tc,ts,x31_0,x31_1
        const f32x4 c2 = *(const f32x4*)&prm[rloc][8];   // Go0,Go1,ho,-
        const f32x4 c3 = *(const f32x4*)&prm[rloc][12];  // C,u,w,pp
        const float A0 = c0.x, tvs = c0.y, tvc = c0.z, A1 = c0.w;
        const float tc = c1.x, ts  = c1.y, x31_0 = c1.z, x31_1 = c1.w;
        const float Go0 = c2.x, Go1 = c2.y, ho = c2.z;
        const float C = c3.x, u = c3.y, w = c3.z, pp = c3.w;

        const unsigned base = (unsigned)row2 * 773u;
        const int ph = (int)(base & 3u);                   // alignment phase
        float* a0p = out + (base & ~3u);

        // ---- compute into LDS (consecutive lanes, conflict-free) ----------
        #pragma unroll
        for (int c = 0; c < 8; ++c) {
            const float ox = gx[c], oy = gy[c];
            const float val = g0lane ? fmaf(oy, tvc, fmaf(-ox, tvs, A0))
                                     : fmaf(oy, ts,  fmaf( ox, tc,  A1));
            wb[ph + 2 + c * 64 + l] = val;
        }
        #pragma unroll
        for (int c = 0; c < 4; ++c) {
            wb[ph + 516 + c * 64 + l] =
                fmaf(pp, hq[c], fmaf(w, hy[c], fmaf(u, hx[c], C)));
        }
        if (l == 0)      { wb[ph + 0]   = x31_0; wb[ph + 1]   = x31_1; }
        else if (l == 1) { wb[ph + 514] = Go0;   wb[ph + 515] = Go1;   }
        else if (l == 2) { wb[ph + 772] = ho; }

        // ---- copy: full chunks 1..192, branchless -------------------------
        #pragma unroll
        for (int q = 0; q < 3; ++q) {
            const int c16 = q * 64 + l + 1;                // 1..192
            *(f32x4*)(a0p + 4 * c16) = *(const f32x4*)&wb[4 * c16];
        }

        // ---- head (lane 0) / tail (lane 1) --------------------------------
        if (l == 0) {
            float* p = out + base;
            if (ph == 0) {
                *(f32x4*)p = *(const f32x4*)&wb[0];
            } else if (ph == 1) {
                p[0] = wb[1];
                *(f32x2*)(p + 1) = (f32x2){wb[2], wb[3]};
            } else if (ph == 2) {
                *(f32x2*)p = (f32x2){wb[2], wb[3]};
            } else {
                p[0] = wb[3];
            }
        } else if (l == 1) {
            float* p = a0p + 772;                          // 16B-aligned
            if (ph == 0) {
                p[0] = wb[772];
            } else if (ph == 1) {
                *(f32x2*)p = (f32x2){wb[772], wb[773]};
            } else if (ph == 2) {
                *(f32x2*)p = (f32x2){wb[772], wb[773]};
                p[2] = wb[774];
            } else {
                *(f32x4*)p = *(const f32x4*)&wb[772];
            }
        }
    }
}

extern "C" void kernel_launch(void* const* d_in, const int* in_sizes, int n_in,
                              void* d_out, int out_size, void* d_ws, size_t ws_size,
                              hipStream_t stream) {
    const float* x          = (const float*)d_in[0];
    const float* obstacles  = (const float*)d_in[1];
    const float* input_mean = (const float*)d_in[2];
    const float* input_std  = (const float*)d_in[3];
    const float* W1  = (const float*)d_in[4];
    const float* b1  = (const float*)d_in[5];
    const float* W21 = (const float*)d_in[6];
    const float* b21 = (const float*)d_in[7];
    const float* W22 = (const float*)d_in[8];
    const float* b22 = (const float*)d_in[9];
    const float* W31 = (const float*)d_in[10];
    const float* b31 = (const float*)d_in[11];
    const float* W32 = (const float*)d_in[12];
    const float* b32 = (const float*)d_in[13];

    float* out = (float*)d_out;

    // 1024 blocks x 4 waves, 64 rows/block; no workspace needed.
    fused2<<<dim3(NB_TOTAL / 64), dim3(256), 0, stream>>>(
        x, obstacles, input_mean, input_std,
        W1, b1, W21, b21, W22, b22, W31, b31, W32, b32, out);
}